// Round 8
// baseline (148.121 us; speedup 1.0000x reference)
//
#include <hip/hip_runtime.h>
#include <hip/hip_bf16.h>
#include <math.h>

#define B_    64
#define L_    2048
#define D_    512
#define EPS   1.5e-3f
#define WREG  48    // W chunks (uint4 = 8 f16) per output in named VGPRs (192 regs)
#define WLDS  16    // tail chunks in LDS (16*512*16B = 128 KB)

typedef _Float16 half2v __attribute__((ext_vector_type(2)));

// Packed f16 dot-2 with f32 accumulate (VOP3P v_dot2_f32_f16 via builtin).
__device__ inline float fdot2f(unsigned wu, unsigned hu, float acc) {
    return __builtin_amdgcn_fdot2(__builtin_bit_cast(half2v, wu),
                                  __builtin_bit_cast(half2v, hu), acc, false);
}

__device__ inline float fast_tanh(float x) {
    float e = __expf(2.0f * x);           // inf for large x is fine
    return 1.0f - 2.0f / (e + 1.0f);
}

// LDS-only barrier: waits for this wave's LDS ops, then raw s_barrier.
// Crucially does NOT drain vmcnt — global output stores stay in flight
// across steps (the __syncthreads vmcnt(0) drain was the R7 regression).
__device__ inline void lds_barrier() {
    asm volatile("s_waitcnt lgkmcnt(0)" ::: "memory");
    __builtin_amdgcn_s_barrier();
    __builtin_amdgcn_sched_barrier(0);
}

__device__ inline int clampc(int c) { return c < 0 ? 0 : (c > L_ ? L_ : c); }

union PackU { unsigned u; _Float16 h[2]; };

// blocks [0,64): u[b][d] = x[b]·W_ih[d] + b_ih[d] + b_hh[d]
// blocks [64,128): transpose+convert W_hh -> WT8 packed f16 pairs:
//   WT8 row k8 in [0,64) holds, per d, uint4 = 4 packed pairs covering k = 8*k8..8*k8+7
__global__ __launch_bounds__(512) void prep_kernel(
    const float* __restrict__ x, const float* __restrict__ W_ih,
    const float* __restrict__ W_hh, const float* __restrict__ b_ih,
    const float* __restrict__ b_hh, uint4* __restrict__ wt8,
    float* __restrict__ u)
{
    const int blk = blockIdx.x;
    const int tid = threadIdx.x;
    if (blk < B_) {
        __shared__ float xs[D_];
        xs[tid] = x[blk * D_ + tid];
        __syncthreads();
        const float4* wrow = reinterpret_cast<const float4*>(W_ih + (size_t)tid * D_);
        const float4* xv   = reinterpret_cast<const float4*>(xs);
        float acc = b_ih[tid] + b_hh[tid];
        #pragma unroll 8
        for (int k = 0; k < D_ / 4; ++k) {
            float4 w = wrow[k]; float4 xx = xv[k];
            acc += w.x * xx.x + w.y * xx.y + w.z * xx.z + w.w * xx.w;
        }
        u[blk * D_ + tid] = acc;
    } else {
        const int k8 = blk - B_;
        const float* wr = W_hh + (size_t)tid * D_ + k8 * 8;
        unsigned o[4];
        #pragma unroll
        for (int j = 0; j < 4; ++j) {
            PackU p;
            p.h[0] = (_Float16)wr[2 * j];
            p.h[1] = (_Float16)wr[2 * j + 1];
            o[j] = p.u;
        }
        wt8[(size_t)k8 * D_ + tid] = make_uint4(o[0], o[1], o[2], o[3]);
    }
}

#define REP48(M) M(0)M(1)M(2)M(3)M(4)M(5)M(6)M(7)M(8)M(9)M(10)M(11)M(12)M(13)\
M(14)M(15)M(16)M(17)M(18)M(19)M(20)M(21)M(22)M(23)M(24)M(25)M(26)M(27)M(28)\
M(29)M(30)M(31)M(32)M(33)M(34)M(35)M(36)M(37)M(38)M(39)M(40)M(41)M(42)M(43)\
M(44)M(45)M(46)M(47)

// 256 blocks x 512 threads, 1 block/CU (LDS 130 KB).
//  blocks [0,64):   RNN for sample b (named regs + builtin dot2, LDS-only barrier).
//  blocks [64,256): zero-fill rows [count, L) concurrently on idle CUs.
__global__ __launch_bounds__(512, 2) void rnn_kernel(
    const int* __restrict__ counts, const float* __restrict__ u,
    const uint4* __restrict__ wt8, float* __restrict__ out,
    float* __restrict__ hA, float* __restrict__ hB, int* __restrict__ tstop)
{
    const int blk = blockIdx.x;
    const int tid = threadIdx.x;

    __shared__ __align__(16) uint4 wl[WLDS][D_];       // 128 KB
    __shared__ __align__(16) _Float16 hbuf[2][D_];     // 2 KB
    __shared__ int flag[2];

    if (blk >= B_) {
        // ---------------- zero-fill path ----------------
        const int idx   = blk - B_;          // 0..191
        const int b     = idx / 3;
        const int chunk = idx % 3;
        const int count = clampc(counts[b]);
        const int rsub  = tid >> 7;          // 0..3
        const int d4    = tid & 127;
        float4* ob = reinterpret_cast<float4*>(out + (size_t)b * L_ * D_);
        const float4 z = make_float4(0.f, 0.f, 0.f, 0.f);
        for (int r = count + chunk * 4 + rsub; r < L_; r += 12)
            ob[(size_t)r * (D_ / 4) + d4] = z;
        return;
    }

    // ---------------- RNN path ----------------
    const int b = blk;
    const int d = tid;
    const int count = clampc(counts[b]);

    const uint4* wp = wt8 + d;
    #define WLOAD(i) uint4 w##i = wp[(size_t)(i) * D_];
    REP48(WLOAD)
    #undef WLOAD
    #pragma unroll
    for (int j = 0; j < WLDS; ++j) wl[j][d] = wp[(size_t)(WREG + j) * D_];

    hbuf[0][d] = (_Float16)0.f;
    if (d == 0) { flag[0] = -2; flag[1] = -2; }

    const float ureg = u[b * D_ + d];
    float* orow = out + (size_t)b * L_ * D_ + d;
    __syncthreads();                         // full drain once (W loads -> LDS)

    float hm1 = 0.f, hm2 = 0.f;
    int   ts  = count;
    float aval = 0.f, bval = 0.f;

    for (int t = 0; t < count; ++t) {
        const uint4* hv = reinterpret_cast<const uint4*>(hbuf[t & 1]);
        float acc0 = ureg, acc1 = 0.f, acc2 = 0.f, acc3 = 0.f;

        // LDS tail chunks (per-lane reads issue early, overlap the reg stream)
        #pragma unroll
        for (int j = 0; j < WLDS; ++j) {
            uint4 hh = hv[WREG + j];
            uint4 xw = wl[j][d];
            acc0 = fdot2f(xw.x, hh.x, acc0); acc1 = fdot2f(xw.y, hh.y, acc1);
            acc2 = fdot2f(xw.z, hh.z, acc2); acc3 = fdot2f(xw.w, hh.w, acc3);
        }
        // named-register chunks
        #define DOTC(i) { uint4 hh = hv[i]; \
            acc0 = fdot2f(w##i.x, hh.x, acc0); acc1 = fdot2f(w##i.y, hh.y, acc1); \
            acc2 = fdot2f(w##i.z, hh.z, acc2); acc3 = fdot2f(w##i.w, hh.w, acc3); }
        REP48(DOTC)
        #undef DOTC

        const float h = fast_tanh((acc0 + acc1) + (acc2 + acc3));
        orow[(size_t)t * D_] = h;            // fire-and-forget; NOT drained per step

        const float df = fabsf(h - hm2);
        hm2 = hm1; hm1 = h;

        hbuf[(t + 1) & 1][d] = (_Float16)h;
        if (t < 2 || df > EPS) flag[t & 1] = t;   // benign same-value race
        lds_barrier();                            // LDS-only visibility + slot reuse
        if (flag[t & 1] != t && flag[(t + 1) & 1] != t - 1) {
            ts   = t + 1;                         // both parities settled
            aval = hm2;                           // row ts     (parity 0) = h_{t-1}
            bval = hm1;                           // row ts + 1 (parity 1) = h_t
            break;
        }
    }

    hA[b * D_ + d] = aval;
    hB[b * D_ + d] = bval;
    if (d == 0) tstop[b] = ts;
}

// Rows [ts,count): alternate hA/hB by parity of (t-ts). (Zeros already written.)
__global__ __launch_bounds__(256) void cfill_kernel(
    const int* __restrict__ counts, const int* __restrict__ tstop,
    const float* __restrict__ hA, const float* __restrict__ hB,
    float* __restrict__ out)
{
    const int b   = blockIdx.y;
    const int c   = blockIdx.x;          // 128 chunks of 16 rows
    const int tid = threadIdx.x;
    const int count = clampc(counts[b]);
    const int ts  = tstop[b];

    const int d4   = tid & 127;
    const int rsub = tid >> 7;           // 0..1
    const float4 av = reinterpret_cast<const float4*>(hA + (size_t)b * D_)[d4];
    const float4 bv = reinterpret_cast<const float4*>(hB + (size_t)b * D_)[d4];
    float4* ob = reinterpret_cast<float4*>(out + (size_t)b * L_ * D_);

    #pragma unroll
    for (int rr = 0; rr < 8; ++rr) {
        const int t = c * 16 + rr * 2 + rsub;
        if (t < ts || t >= count) continue;
        ob[(size_t)t * (D_ / 4) + d4] = ((t - ts) & 1) ? bv : av;
    }
}

extern "C" void kernel_launch(void* const* d_in, const int* in_sizes, int n_in,
                              void* d_out, int out_size, void* d_ws, size_t ws_size,
                              hipStream_t stream) {
    const int*   counts = (const int*)d_in[0];
    const float* x      = (const float*)d_in[1];
    const float* W_ih   = (const float*)d_in[2];
    const float* W_hh   = (const float*)d_in[3];
    const float* b_ih   = (const float*)d_in[4];
    const float* b_hh   = (const float*)d_in[5];
    float* out = (float*)d_out;

    char* ws = (char*)d_ws;
    uint4* wt8 = (uint4*)ws;                                   // 512 KB
    float* u   = (float*)(ws + (512 << 10));                   // 128 KB
    float* hA  = (float*)(ws + (512 << 10) + (128 << 10));     // 128 KB
    float* hB  = (float*)(ws + (512 << 10) + (256 << 10));     // 128 KB
    int*   tstop = (int*)(ws + (512 << 10) + (384 << 10));     // 256 B

    hipLaunchKernelGGL(prep_kernel, dim3(128), dim3(512), 0, stream,
                       x, W_ih, W_hh, b_ih, b_hh, wt8, u);
    hipLaunchKernelGGL(rnn_kernel, dim3(256), dim3(512), 0, stream,
                       counts, u, wt8, out, hA, hB, tstop);
    hipLaunchKernelGGL(cfill_kernel, dim3(128, B_), dim3(256), 0, stream,
                       counts, tstop, hA, hB, out);
}

// Round 9
// 147.803 us; speedup vs baseline: 1.0021x; 1.0021x over previous
//
#include <hip/hip_runtime.h>
#include <hip/hip_bf16.h>
#include <math.h>

#define B_    64
#define L_    2048
#define D_    512
#define EPS   1.5e-3f
#define WREG  48    // W chunks (uint4 = 8 f16) per output in named VGPRs (192 regs)
#define WLDS  16    // tail chunks in LDS (16*512*16B = 128 KB)

typedef _Float16 half2v __attribute__((ext_vector_type(2)));

// Packed f16 dot-2 with f32 accumulate (VOP3P v_dot2_f32_f16 via builtin).
__device__ inline float fdot2f(unsigned wu, unsigned hu, float acc) {
    return __builtin_amdgcn_fdot2(__builtin_bit_cast(half2v, wu),
                                  __builtin_bit_cast(half2v, hu), acc, false);
}

__device__ inline float fast_tanh(float x) {
    float e = __expf(2.0f * x);           // inf for large x is fine
    return 1.0f - 2.0f / (e + 1.0f);
}

// LDS-only barrier: waits for this wave's LDS ops, then raw s_barrier.
// Does not drain vmcnt (output stores stay in flight across steps).
__device__ inline void lds_barrier() {
    asm volatile("s_waitcnt lgkmcnt(0)" ::: "memory");
    __builtin_amdgcn_s_barrier();
    __builtin_amdgcn_sched_barrier(0);
}

__device__ inline int clampc(int c) { return c < 0 ? 0 : (c > L_ ? L_ : c); }

union PackU { unsigned u; _Float16 h[2]; };

// blocks [0,64): u[b][d] = x[b]·W_ih[d] + b_ih[d] + b_hh[d]
// blocks [64,128): transpose+convert W_hh -> WT8 packed f16 pairs:
//   WT8 row k8 in [0,64) holds, per d, uint4 = 4 packed pairs covering k = 8*k8..8*k8+7
__global__ __launch_bounds__(512) void prep_kernel(
    const float* __restrict__ x, const float* __restrict__ W_ih,
    const float* __restrict__ W_hh, const float* __restrict__ b_ih,
    const float* __restrict__ b_hh, uint4* __restrict__ wt8,
    float* __restrict__ u)
{
    const int blk = blockIdx.x;
    const int tid = threadIdx.x;
    if (blk < B_) {
        __shared__ float xs[D_];
        xs[tid] = x[blk * D_ + tid];
        __syncthreads();
        const float4* wrow = reinterpret_cast<const float4*>(W_ih + (size_t)tid * D_);
        const float4* xv   = reinterpret_cast<const float4*>(xs);
        float acc = b_ih[tid] + b_hh[tid];
        #pragma unroll 8
        for (int k = 0; k < D_ / 4; ++k) {
            float4 w = wrow[k]; float4 xx = xv[k];
            acc += w.x * xx.x + w.y * xx.y + w.z * xx.z + w.w * xx.w;
        }
        u[blk * D_ + tid] = acc;
    } else {
        const int k8 = blk - B_;
        const float* wr = W_hh + (size_t)tid * D_ + k8 * 8;
        unsigned o[4];
        #pragma unroll
        for (int j = 0; j < 4; ++j) {
            PackU p;
            p.h[0] = (_Float16)wr[2 * j];
            p.h[1] = (_Float16)wr[2 * j + 1];
            o[j] = p.u;
        }
        wt8[(size_t)k8 * D_ + tid] = make_uint4(o[0], o[1], o[2], o[3]);
    }
}

#define REP48(M) M(0)M(1)M(2)M(3)M(4)M(5)M(6)M(7)M(8)M(9)M(10)M(11)M(12)M(13)\
M(14)M(15)M(16)M(17)M(18)M(19)M(20)M(21)M(22)M(23)M(24)M(25)M(26)M(27)M(28)\
M(29)M(30)M(31)M(32)M(33)M(34)M(35)M(36)M(37)M(38)M(39)M(40)M(41)M(42)M(43)\
M(44)M(45)M(46)M(47)

// 256 blocks x 512 threads, 1 block/CU (LDS 130 KB).
//  blocks [0,64):   RNN for sample b (named regs + builtin dot2, LDS-only barrier).
//  blocks [64,256): zero-fill rows [count, L) in CONTIGUOUS per-block slabs
//                   (the strided r+=12 pattern was the 116-us HBM thrash).
__global__ __launch_bounds__(512, 2) void rnn_kernel(
    const int* __restrict__ counts, const float* __restrict__ u,
    const uint4* __restrict__ wt8, float* __restrict__ out,
    float* __restrict__ hA, float* __restrict__ hB, int* __restrict__ tstop)
{
    const int blk = blockIdx.x;
    const int tid = threadIdx.x;

    __shared__ __align__(16) uint4 wl[WLDS][D_];       // 128 KB
    __shared__ __align__(16) _Float16 hbuf[2][D_];     // 2 KB
    __shared__ int flag[2];

    if (blk >= B_) {
        // ------------- zero-fill path: contiguous slab per block -------------
        const int idx   = blk - B_;          // 0..191
        const int b     = idx / 3;
        const int chunk = idx % 3;
        const int count = clampc(counts[b]);
        const int Z     = L_ - count;        // zero rows for this sample
        const int len   = (Z + 2) / 3;       // slab length (contiguous third)
        const int r0    = count + chunk * len;
        const int r1    = (r0 + len < L_) ? (r0 + len) : L_;
        const int rsub  = tid >> 7;          // 0..3
        const int d4    = tid & 127;
        float4* ob = reinterpret_cast<float4*>(out + (size_t)b * L_ * D_);
        const float4 z = make_float4(0.f, 0.f, 0.f, 0.f);
        // 4 consecutive rows (8 KB contiguous) per iteration, streaming slab
        for (int r = r0 + rsub; r < r1; r += 4)
            ob[(size_t)r * (D_ / 4) + d4] = z;
        return;
    }

    // ---------------- RNN path ----------------
    const int b = blk;
    const int d = tid;
    const int count = clampc(counts[b]);

    const uint4* wp = wt8 + d;
    #define WLOAD(i) uint4 w##i = wp[(size_t)(i) * D_];
    REP48(WLOAD)
    #undef WLOAD
    #pragma unroll
    for (int j = 0; j < WLDS; ++j) wl[j][d] = wp[(size_t)(WREG + j) * D_];

    hbuf[0][d] = (_Float16)0.f;
    if (d == 0) { flag[0] = -2; flag[1] = -2; }

    const float ureg = u[b * D_ + d];
    float* orow = out + (size_t)b * L_ * D_ + d;
    __syncthreads();                         // full drain once (W loads -> LDS)

    float hm1 = 0.f, hm2 = 0.f;
    int   ts  = count;
    float aval = 0.f, bval = 0.f;

    for (int t = 0; t < count; ++t) {
        const uint4* hv = reinterpret_cast<const uint4*>(hbuf[t & 1]);
        float acc0 = ureg, acc1 = 0.f, acc2 = 0.f, acc3 = 0.f;

        // LDS tail chunks (per-lane reads issue early, overlap the reg stream)
        #pragma unroll
        for (int j = 0; j < WLDS; ++j) {
            uint4 hh = hv[WREG + j];
            uint4 xw = wl[j][d];
            acc0 = fdot2f(xw.x, hh.x, acc0); acc1 = fdot2f(xw.y, hh.y, acc1);
            acc2 = fdot2f(xw.z, hh.z, acc2); acc3 = fdot2f(xw.w, hh.w, acc3);
        }
        // named-register chunks
        #define DOTC(i) { uint4 hh = hv[i]; \
            acc0 = fdot2f(w##i.x, hh.x, acc0); acc1 = fdot2f(w##i.y, hh.y, acc1); \
            acc2 = fdot2f(w##i.z, hh.z, acc2); acc3 = fdot2f(w##i.w, hh.w, acc3); }
        REP48(DOTC)
        #undef DOTC

        const float h = fast_tanh((acc0 + acc1) + (acc2 + acc3));
        orow[(size_t)t * D_] = h;            // fire-and-forget

        const float df = fabsf(h - hm2);
        hm2 = hm1; hm1 = h;

        hbuf[(t + 1) & 1][d] = (_Float16)h;
        if (t < 2 || df > EPS) flag[t & 1] = t;   // benign same-value race
        lds_barrier();                            // LDS-only visibility + slot reuse
        if (flag[t & 1] != t && flag[(t + 1) & 1] != t - 1) {
            ts   = t + 1;                         // both parities settled
            aval = hm2;                           // row ts     (parity 0) = h_{t-1}
            bval = hm1;                           // row ts + 1 (parity 1) = h_t
            break;
        }
    }

    hA[b * D_ + d] = aval;
    hB[b * D_ + d] = bval;
    if (d == 0) tstop[b] = ts;
}

// Rows [ts,count): alternate hA/hB by parity of (t-ts). (Zeros already written.)
__global__ __launch_bounds__(256) void cfill_kernel(
    const int* __restrict__ counts, const int* __restrict__ tstop,
    const float* __restrict__ hA, const float* __restrict__ hB,
    float* __restrict__ out)
{
    const int b   = blockIdx.y;
    const int c   = blockIdx.x;          // 128 chunks of 16 rows
    const int tid = threadIdx.x;
    const int count = clampc(counts[b]);
    const int ts  = tstop[b];

    const int d4   = tid & 127;
    const int rsub = tid >> 7;           // 0..1
    const float4 av = reinterpret_cast<const float4*>(hA + (size_t)b * D_)[d4];
    const float4 bv = reinterpret_cast<const float4*>(hB + (size_t)b * D_)[d4];
    float4* ob = reinterpret_cast<float4*>(out + (size_t)b * L_ * D_);

    #pragma unroll
    for (int rr = 0; rr < 8; ++rr) {
        const int t = c * 16 + rr * 2 + rsub;
        if (t < ts || t >= count) continue;
        ob[(size_t)t * (D_ / 4) + d4] = ((t - ts) & 1) ? bv : av;
    }
}

extern "C" void kernel_launch(void* const* d_in, const int* in_sizes, int n_in,
                              void* d_out, int out_size, void* d_ws, size_t ws_size,
                              hipStream_t stream) {
    const int*   counts = (const int*)d_in[0];
    const float* x      = (const float*)d_in[1];
    const float* W_ih   = (const float*)d_in[2];
    const float* W_hh   = (const float*)d_in[3];
    const float* b_ih   = (const float*)d_in[4];
    const float* b_hh   = (const float*)d_in[5];
    float* out = (float*)d_out;

    char* ws = (char*)d_ws;
    uint4* wt8 = (uint4*)ws;                                   // 512 KB
    float* u   = (float*)(ws + (512 << 10));                   // 128 KB
    float* hA  = (float*)(ws + (512 << 10) + (128 << 10));     // 128 KB
    float* hB  = (float*)(ws + (512 << 10) + (256 << 10));     // 128 KB
    int*   tstop = (int*)(ws + (512 << 10) + (384 << 10));     // 256 B

    hipLaunchKernelGGL(prep_kernel, dim3(128), dim3(512), 0, stream,
                       x, W_ih, W_hh, b_ih, b_hh, wt8, u);
    hipLaunchKernelGGL(rnn_kernel, dim3(256), dim3(512), 0, stream,
                       counts, u, wt8, out, hA, hB, tstop);
    hipLaunchKernelGGL(cfill_kernel, dim3(128, B_), dim3(256), 0, stream,
                       counts, tstop, hA, hB, out);
}

// Round 10
// 127.952 us; speedup vs baseline: 1.1576x; 1.1551x over previous
//
#include <hip/hip_runtime.h>
#include <hip/hip_bf16.h>
#include <math.h>

#define B_    64
#define L_    2048
#define D_    512
#define EPS   1.5e-3f
#define WREG  48    // W chunks (uint4 = 8 f16) per OUTPUT in named VGPRs
#define WLDS  16    // tail chunks per output in LDS (2*16*256*16B = 128 KB)

typedef _Float16 half2v __attribute__((ext_vector_type(2)));

// Packed f16 dot-2 with f32 accumulate (VOP3P v_dot2_f32_f16 via builtin).
__device__ inline float fdot2f(unsigned wu, unsigned hu, float acc) {
    return __builtin_amdgcn_fdot2(__builtin_bit_cast(half2v, wu),
                                  __builtin_bit_cast(half2v, hu), acc, false);
}

__device__ inline float fast_tanh(float x) {
    float e = __expf(2.0f * x);           // inf for large x is fine
    return 1.0f - 2.0f / (e + 1.0f);
}

// LDS-only barrier: waits this wave's LDS ops, then raw s_barrier.
// Does not drain vmcnt — output stores stay in flight across steps.
__device__ inline void lds_barrier() {
    asm volatile("s_waitcnt lgkmcnt(0)" ::: "memory");
    __builtin_amdgcn_s_barrier();
    __builtin_amdgcn_sched_barrier(0);
}

__device__ inline int clampc(int c) { return c < 0 ? 0 : (c > L_ ? L_ : c); }

union PackU { unsigned u; _Float16 h[2]; };

// blocks [0,64): u[b][d] = x[b]·W_ih[d] + b_ih[d] + b_hh[d]
// blocks [64,128): transpose+convert W_hh -> WT8 packed f16 pairs:
//   WT8 row k8 in [0,64) holds, per d, uint4 = 4 packed pairs covering k = 8*k8..8*k8+7
__global__ __launch_bounds__(512) void prep_kernel(
    const float* __restrict__ x, const float* __restrict__ W_ih,
    const float* __restrict__ W_hh, const float* __restrict__ b_ih,
    const float* __restrict__ b_hh, uint4* __restrict__ wt8,
    float* __restrict__ u)
{
    const int blk = blockIdx.x;
    const int tid = threadIdx.x;
    if (blk < B_) {
        __shared__ float xs[D_];
        xs[tid] = x[blk * D_ + tid];
        __syncthreads();
        const float4* wrow = reinterpret_cast<const float4*>(W_ih + (size_t)tid * D_);
        const float4* xv   = reinterpret_cast<const float4*>(xs);
        float acc = b_ih[tid] + b_hh[tid];
        #pragma unroll 8
        for (int k = 0; k < D_ / 4; ++k) {
            float4 w = wrow[k]; float4 xx = xv[k];
            acc += w.x * xx.x + w.y * xx.y + w.z * xx.z + w.w * xx.w;
        }
        u[blk * D_ + tid] = acc;
    } else {
        const int k8 = blk - B_;
        const float* wr = W_hh + (size_t)tid * D_ + k8 * 8;
        unsigned o[4];
        #pragma unroll
        for (int j = 0; j < 4; ++j) {
            PackU p;
            p.h[0] = (_Float16)wr[2 * j];
            p.h[1] = (_Float16)wr[2 * j + 1];
            o[j] = p.u;
        }
        wt8[(size_t)k8 * D_ + tid] = make_uint4(o[0], o[1], o[2], o[3]);
    }
}

#define REP48(M) M(0)M(1)M(2)M(3)M(4)M(5)M(6)M(7)M(8)M(9)M(10)M(11)M(12)M(13)\
M(14)M(15)M(16)M(17)M(18)M(19)M(20)M(21)M(22)M(23)M(24)M(25)M(26)M(27)M(28)\
M(29)M(30)M(31)M(32)M(33)M(34)M(35)M(36)M(37)M(38)M(39)M(40)M(41)M(42)M(43)\
M(44)M(45)M(46)M(47)

// 64 blocks x 256 threads, 1 sample/block; thread t owns outputs t and t+256.
// Halves the wave count vs 512-thr: the uniform h-broadcast LDS reads (the
// measured step-time dominator) are per-wave, so 8->4 waves halves that cost
// while the h data consumed per thread doubles-for-free (2 outputs share hv).
// W per output: 48 named-VGPR chunks (2x192 = 384 regs, cap 512 @ (256,1))
// + 16 LDS chunks. Early exit on both-parity period-2 fixed point.
__global__ __launch_bounds__(256, 1) void rnn_kernel(
    const int* __restrict__ counts, const float* __restrict__ u,
    const uint4* __restrict__ wt8, float* __restrict__ out,
    float* __restrict__ hA, float* __restrict__ hB, int* __restrict__ tstop)
{
    const int b = blockIdx.x;
    const int tid = threadIdx.x;
    const int d0 = tid;
    const int d1 = tid + 256;
    const int count = clampc(counts[b]);

    __shared__ __align__(16) uint4 wl[2][WLDS][256];   // 128 KB
    __shared__ __align__(16) _Float16 hbuf[2][D_];     // 2 KB
    __shared__ int flag[2];

    const uint4* wpa = wt8 + d0;
    const uint4* wpb = wt8 + d1;
    #define WLOADA(i) uint4 a##i = wpa[(size_t)(i) * D_];
    #define WLOADB(i) uint4 b##i = wpb[(size_t)(i) * D_];
    REP48(WLOADA)
    REP48(WLOADB)
    #undef WLOADA
    #undef WLOADB
    #pragma unroll
    for (int j = 0; j < WLDS; ++j) {
        wl[0][j][tid] = wpa[(size_t)(WREG + j) * D_];
        wl[1][j][tid] = wpb[(size_t)(WREG + j) * D_];
    }

    hbuf[0][d0] = (_Float16)0.f;
    hbuf[0][d1] = (_Float16)0.f;
    if (tid == 0) { flag[0] = -2; flag[1] = -2; }

    const float u0 = u[b * D_ + d0];
    const float u1 = u[b * D_ + d1];
    float* o0 = out + (size_t)b * L_ * D_ + d0;
    float* o1 = out + (size_t)b * L_ * D_ + d1;
    __syncthreads();                         // full drain once (W loads -> LDS)

    float h0m1 = 0.f, h0m2 = 0.f, h1m1 = 0.f, h1m2 = 0.f;
    int   ts = count;
    float a0v = 0.f, b0v = 0.f, a1v = 0.f, b1v = 0.f;

    for (int t = 0; t < count; ++t) {
        const uint4* hv = reinterpret_cast<const uint4*>(hbuf[t & 1]);
        float accA0 = u0, accA1 = 0.f, accA2 = 0.f, accA3 = 0.f;
        float accB0 = u1, accB1 = 0.f, accB2 = 0.f, accB3 = 0.f;

        // LDS tail chunks (per-lane reads issue early, overlap the reg stream)
        #pragma unroll
        for (int j = 0; j < WLDS; ++j) {
            uint4 hh = hv[WREG + j];
            uint4 xa = wl[0][j][tid];
            uint4 xb = wl[1][j][tid];
            accA0 = fdot2f(xa.x, hh.x, accA0); accA1 = fdot2f(xa.y, hh.y, accA1);
            accA2 = fdot2f(xa.z, hh.z, accA2); accA3 = fdot2f(xa.w, hh.w, accA3);
            accB0 = fdot2f(xb.x, hh.x, accB0); accB1 = fdot2f(xb.y, hh.y, accB1);
            accB2 = fdot2f(xb.z, hh.z, accB2); accB3 = fdot2f(xb.w, hh.w, accB3);
        }
        // named-register chunks: one uniform hv read feeds BOTH outputs
        #define DOTC(i) { uint4 hh = hv[i]; \
            accA0 = fdot2f(a##i.x, hh.x, accA0); accA1 = fdot2f(a##i.y, hh.y, accA1); \
            accA2 = fdot2f(a##i.z, hh.z, accA2); accA3 = fdot2f(a##i.w, hh.w, accA3); \
            accB0 = fdot2f(b##i.x, hh.x, accB0); accB1 = fdot2f(b##i.y, hh.y, accB1); \
            accB2 = fdot2f(b##i.z, hh.z, accB2); accB3 = fdot2f(b##i.w, hh.w, accB3); }
        REP48(DOTC)
        #undef DOTC

        const float h0 = fast_tanh((accA0 + accA1) + (accA2 + accA3));
        const float h1 = fast_tanh((accB0 + accB1) + (accB2 + accB3));
        o0[(size_t)t * D_] = h0;             // fire-and-forget
        o1[(size_t)t * D_] = h1;

        const float df = fmaxf(fabsf(h0 - h0m2), fabsf(h1 - h1m2));
        h0m2 = h0m1; h0m1 = h0;
        h1m2 = h1m1; h1m1 = h1;

        hbuf[(t + 1) & 1][d0] = (_Float16)h0;
        hbuf[(t + 1) & 1][d1] = (_Float16)h1;
        if (t < 2 || df > EPS) flag[t & 1] = t;   // benign same-value race
        lds_barrier();                            // LDS visibility + slot reuse
        if (flag[t & 1] != t && flag[(t + 1) & 1] != t - 1) {
            ts  = t + 1;                          // both parities settled
            a0v = h0m2; b0v = h0m1;               // row ts / ts+1 values
            a1v = h1m2; b1v = h1m1;
            break;
        }
    }

    hA[b * D_ + d0] = a0v;  hA[b * D_ + d1] = a1v;
    hB[b * D_ + d0] = b0v;  hB[b * D_ + d1] = b1v;
    if (tid == 0) tstop[b] = ts;
}

// Rows [ts,count): alternate hA/hB by parity of (t-ts). Rows [count,L): zeros.
__global__ __launch_bounds__(256) void fill_kernel(
    const int* __restrict__ counts, const int* __restrict__ tstop,
    const float* __restrict__ hA, const float* __restrict__ hB,
    float* __restrict__ out)
{
    const int b   = blockIdx.y;
    const int c   = blockIdx.x;          // 128 chunks of 16 rows
    const int tid = threadIdx.x;
    const int count = clampc(counts[b]);
    const int ts  = tstop[b];

    const int d4   = tid & 127;
    const int rsub = tid >> 7;           // 0..1
    const float4 av = reinterpret_cast<const float4*>(hA + (size_t)b * D_)[d4];
    const float4 bv = reinterpret_cast<const float4*>(hB + (size_t)b * D_)[d4];
    const float4 z  = make_float4(0.f, 0.f, 0.f, 0.f);
    float4* ob = reinterpret_cast<float4*>(out + (size_t)b * L_ * D_);

    #pragma unroll
    for (int rr = 0; rr < 8; ++rr) {
        const int t = c * 16 + rr * 2 + rsub;
        if (t < ts) continue;
        float4 v = z;
        if (t < count) v = ((t - ts) & 1) ? bv : av;
        ob[(size_t)t * (D_ / 4) + d4] = v;
    }
}

extern "C" void kernel_launch(void* const* d_in, const int* in_sizes, int n_in,
                              void* d_out, int out_size, void* d_ws, size_t ws_size,
                              hipStream_t stream) {
    const int*   counts = (const int*)d_in[0];
    const float* x      = (const float*)d_in[1];
    const float* W_ih   = (const float*)d_in[2];
    const float* W_hh   = (const float*)d_in[3];
    const float* b_ih   = (const float*)d_in[4];
    const float* b_hh   = (const float*)d_in[5];
    float* out = (float*)d_out;

    char* ws = (char*)d_ws;
    uint4* wt8 = (uint4*)ws;                                   // 512 KB
    float* u   = (float*)(ws + (512 << 10));                   // 128 KB
    float* hA  = (float*)(ws + (512 << 10) + (128 << 10));     // 128 KB
    float* hB  = (float*)(ws + (512 << 10) + (256 << 10));     // 128 KB
    int*   tstop = (int*)(ws + (512 << 10) + (384 << 10));     // 256 B

    hipLaunchKernelGGL(prep_kernel, dim3(128), dim3(512), 0, stream,
                       x, W_ih, W_hh, b_ih, b_hh, wt8, u);
    hipLaunchKernelGGL(rnn_kernel, dim3(B_), dim3(256), 0, stream,
                       counts, u, wt8, out, hA, hB, tstop);
    hipLaunchKernelGGL(fill_kernel, dim3(128, B_), dim3(256), 0, stream,
                       counts, tstop, hA, hB, out);
}

// Round 11
// 98.837 us; speedup vs baseline: 1.4986x; 1.2946x over previous
//
#include <hip/hip_runtime.h>
#include <hip/hip_bf16.h>
#include <math.h>

#define B_    64
#define L_    2048
#define D_    512
#define EPS   1.5e-3f

typedef _Float16 half2v __attribute__((ext_vector_type(2)));

// Packed f16 dot-2 with f32 accumulate (VOP3P v_dot2_f32_f16 via builtin).
__device__ inline float fdot2f(unsigned wu, unsigned hu, float acc) {
    return __builtin_amdgcn_fdot2(__builtin_bit_cast(half2v, wu),
                                  __builtin_bit_cast(half2v, hu), acc, false);
}

__device__ inline float fast_tanh(float x) {
    float e = __expf(2.0f * x);           // inf for large x is fine
    return 1.0f - 2.0f / (e + 1.0f);
}

// LDS-only barrier: waits this wave's LDS ops, then raw s_barrier.
// Does not drain vmcnt — output stores stay in flight across steps.
__device__ inline void lds_barrier() {
    asm volatile("s_waitcnt lgkmcnt(0)" ::: "memory");
    __builtin_amdgcn_s_barrier();
    __builtin_amdgcn_sched_barrier(0);
}

__device__ inline int clampc(int c) { return c < 0 ? 0 : (c > L_ ? L_ : c); }

union PackU { unsigned u; _Float16 h[2]; };

// blocks [0,64): u[b][d] = x[b]·W_ih[d] + b_ih[d] + b_hh[d]
// blocks [64,128): transpose+convert W_hh -> WT8 packed f16 pairs, PERMUTED:
//   entry [k8*512 + j*64 + lane] = W_hh[d=lane*8+j][8*k8 .. 8*k8+7]
//   so rnn's wave-sliced per-lane loads (j fixed, lane consecutive) coalesce.
__global__ __launch_bounds__(512) void prep_kernel(
    const float* __restrict__ x, const float* __restrict__ W_ih,
    const float* __restrict__ W_hh, const float* __restrict__ b_ih,
    const float* __restrict__ b_hh, uint4* __restrict__ wt8,
    float* __restrict__ u)
{
    const int blk = blockIdx.x;
    const int tid = threadIdx.x;
    if (blk < B_) {
        __shared__ float xs[D_];
        xs[tid] = x[blk * D_ + tid];
        __syncthreads();
        const float4* wrow = reinterpret_cast<const float4*>(W_ih + (size_t)tid * D_);
        const float4* xv   = reinterpret_cast<const float4*>(xs);
        float acc = b_ih[tid] + b_hh[tid];
        #pragma unroll 8
        for (int k = 0; k < D_ / 4; ++k) {
            float4 w = wrow[k]; float4 xx = xv[k];
            acc += w.x * xx.x + w.y * xx.y + w.z * xx.z + w.w * xx.w;
        }
        u[blk * D_ + tid] = acc;
    } else {
        const int k8   = blk - B_;
        const int j    = tid >> 6;          // 0..7
        const int lane = tid & 63;
        const int d    = lane * 8 + j;
        const float* wr = W_hh + (size_t)d * D_ + k8 * 8;
        unsigned o[4];
        #pragma unroll
        for (int i = 0; i < 4; ++i) {
            PackU p;
            p.h[0] = (_Float16)wr[2 * i];
            p.h[1] = (_Float16)wr[2 * i + 1];
            o[i] = p.u;
        }
        wt8[(size_t)k8 * D_ + j * 64 + lane] = make_uint4(o[0], o[1], o[2], o[3]);
    }
}

// 64 blocks x 512 threads, 1 sample/block. K-SPLIT ACROSS WAVES:
//   wave w owns K-chunks [8w, 8w+8) (k in [64w,64w+64)); each lane computes
//   partial dots for 8 outputs d = lane*8+j over that slice. Uniform h reads
//   drop from 64/thread-step to 8/wave-step (the R6 LDS-pipe dominator).
//   Partials -> pbuf -> thread d=tid reduces, tanh, writes out + hbuf.
// W per lane: j=0..5 in named VGPRs (48 uint4), j=6,7 in LDS (128 KB).
__global__ __launch_bounds__(512, 2) void rnn_kernel(
    const int* __restrict__ counts, const float* __restrict__ u,
    const uint4* __restrict__ wt8, float* __restrict__ out,
    float* __restrict__ hA, float* __restrict__ hB, int* __restrict__ tstop)
{
    const int b    = blockIdx.x;
    const int tid  = threadIdx.x;
    const int w    = tid >> 6;     // wave 0..7
    const int lane = tid & 63;
    const int w8   = w * 8;        // first owned chunk
    const int count = clampc(counts[b]);

    __shared__ __align__(16) uint4 wl[2][8][512];      // 128 KB (j=6,7 tails)
    __shared__ __align__(16) float pbuf[8][D_];        // 16 KB partials
    __shared__ __align__(16) _Float16 hbuf[2][D_];     // 2 KB
    __shared__ int flag[2];

    // W loads (coalesced: lane-consecutive within each (j,c) slice)
    const uint4* wb = wt8 + (size_t)w8 * D_ + lane;
    #define WDEC(j) \
        uint4 w##j##_0 = wb[0*D_ + (j)*64]; uint4 w##j##_1 = wb[1*D_ + (j)*64]; \
        uint4 w##j##_2 = wb[2*D_ + (j)*64]; uint4 w##j##_3 = wb[3*D_ + (j)*64]; \
        uint4 w##j##_4 = wb[4*D_ + (j)*64]; uint4 w##j##_5 = wb[5*D_ + (j)*64]; \
        uint4 w##j##_6 = wb[6*D_ + (j)*64]; uint4 w##j##_7 = wb[7*D_ + (j)*64];
    WDEC(0) WDEC(1) WDEC(2) WDEC(3) WDEC(4) WDEC(5)
    #undef WDEC
    #pragma unroll
    for (int c = 0; c < 8; ++c) {
        wl[0][c][tid] = wb[c * D_ + 6 * 64];
        wl[1][c][tid] = wb[c * D_ + 7 * 64];
    }

    hbuf[0][tid] = (_Float16)0.f;
    if (tid == 0) { flag[0] = -2; flag[1] = -2; }

    const float u_reg = u[b * D_ + tid];
    float* orow = out + (size_t)b * L_ * D_ + tid;
    // reduce-phase source index for output d = tid
    const int Lh = tid >> 3, jh = tid & 7;
    const int pidx = (jh < 4) ? (Lh * 4 + jh) : (256 + Lh * 4 + (jh - 4));
    __syncthreads();                       // full drain once (W loads -> LDS)

    float hm1 = 0.f, hm2 = 0.f;
    int   ts  = count;
    float aval = 0.f, bval = 0.f;

    for (int t = 0; t < count; ++t) {
        // ---------- phase 1: per-wave K-slice partials ----------
        const uint4* hv = reinterpret_cast<const uint4*>(hbuf[t & 1]);
        float p0 = 0.f, p1 = 0.f, p2 = 0.f, p3 = 0.f;
        float p4 = 0.f, p5 = 0.f, p6 = 0.f, p7 = 0.f;

        #define STEPC(c) { \
            uint4 hh = hv[w8 + (c)]; \
            p0 = fdot2f(w0_##c.x, hh.x, p0); p0 = fdot2f(w0_##c.y, hh.y, p0); \
            p0 = fdot2f(w0_##c.z, hh.z, p0); p0 = fdot2f(w0_##c.w, hh.w, p0); \
            p1 = fdot2f(w1_##c.x, hh.x, p1); p1 = fdot2f(w1_##c.y, hh.y, p1); \
            p1 = fdot2f(w1_##c.z, hh.z, p1); p1 = fdot2f(w1_##c.w, hh.w, p1); \
            p2 = fdot2f(w2_##c.x, hh.x, p2); p2 = fdot2f(w2_##c.y, hh.y, p2); \
            p2 = fdot2f(w2_##c.z, hh.z, p2); p2 = fdot2f(w2_##c.w, hh.w, p2); \
            p3 = fdot2f(w3_##c.x, hh.x, p3); p3 = fdot2f(w3_##c.y, hh.y, p3); \
            p3 = fdot2f(w3_##c.z, hh.z, p3); p3 = fdot2f(w3_##c.w, hh.w, p3); \
            p4 = fdot2f(w4_##c.x, hh.x, p4); p4 = fdot2f(w4_##c.y, hh.y, p4); \
            p4 = fdot2f(w4_##c.z, hh.z, p4); p4 = fdot2f(w4_##c.w, hh.w, p4); \
            p5 = fdot2f(w5_##c.x, hh.x, p5); p5 = fdot2f(w5_##c.y, hh.y, p5); \
            p5 = fdot2f(w5_##c.z, hh.z, p5); p5 = fdot2f(w5_##c.w, hh.w, p5); \
            uint4 x6 = wl[0][c][tid]; \
            p6 = fdot2f(x6.x, hh.x, p6); p6 = fdot2f(x6.y, hh.y, p6); \
            p6 = fdot2f(x6.z, hh.z, p6); p6 = fdot2f(x6.w, hh.w, p6); \
            uint4 x7 = wl[1][c][tid]; \
            p7 = fdot2f(x7.x, hh.x, p7); p7 = fdot2f(x7.y, hh.y, p7); \
            p7 = fdot2f(x7.z, hh.z, p7); p7 = fdot2f(x7.w, hh.w, p7); }
        STEPC(0) STEPC(1) STEPC(2) STEPC(3)
        STEPC(4) STEPC(5) STEPC(6) STEPC(7)
        #undef STEPC

        // partials: pbuf[w][lane*4 + i] (j<4), pbuf[w][256 + lane*4 + i] (j>=4)
        float4* pw = reinterpret_cast<float4*>(&pbuf[w][0]);
        pw[lane]      = make_float4(p0, p1, p2, p3);
        pw[64 + lane] = make_float4(p4, p5, p6, p7);
        lds_barrier();                     // partials visible

        // ---------- phase 2: reduce output d = tid ----------
        float s = u_reg;
        #pragma unroll
        for (int w2 = 0; w2 < 8; ++w2) s += pbuf[w2][pidx];

        const float h = fast_tanh(s);
        orow[(size_t)t * D_] = h;          // fire-and-forget

        const float df = fabsf(h - hm2);
        hm2 = hm1; hm1 = h;

        hbuf[(t + 1) & 1][tid] = (_Float16)h;
        if (t < 2 || df > EPS) flag[t & 1] = t;   // benign same-value race
        lds_barrier();                     // h + flag visible; orders pbuf reuse
        if (flag[t & 1] != t && flag[(t + 1) & 1] != t - 1) {
            ts   = t + 1;                  // both parities settled
            aval = hm2;                    // row ts     (parity 0) = h_{t-1}
            bval = hm1;                    // row ts + 1 (parity 1) = h_t
            break;
        }
    }

    hA[b * D_ + tid] = aval;
    hB[b * D_ + tid] = bval;
    if (tid == 0) tstop[b] = ts;
}

// Rows [ts,count): alternate hA/hB by parity of (t-ts). Rows [count,L): zeros.
__global__ __launch_bounds__(256) void fill_kernel(
    const int* __restrict__ counts, const int* __restrict__ tstop,
    const float* __restrict__ hA, const float* __restrict__ hB,
    float* __restrict__ out)
{
    const int b   = blockIdx.y;
    const int c   = blockIdx.x;          // 128 chunks of 16 rows
    const int tid = threadIdx.x;
    const int count = clampc(counts[b]);
    const int ts  = tstop[b];

    const int d4   = tid & 127;
    const int rsub = tid >> 7;           // 0..1
    const float4 av = reinterpret_cast<const float4*>(hA + (size_t)b * D_)[d4];
    const float4 bv = reinterpret_cast<const float4*>(hB + (size_t)b * D_)[d4];
    const float4 z  = make_float4(0.f, 0.f, 0.f, 0.f);
    float4* ob = reinterpret_cast<float4*>(out + (size_t)b * L_ * D_);

    #pragma unroll
    for (int rr = 0; rr < 8; ++rr) {
        const int t = c * 16 + rr * 2 + rsub;
        if (t < ts) continue;
        float4 v = z;
        if (t < count) v = ((t - ts) & 1) ? bv : av;
        ob[(size_t)t * (D_ / 4) + d4] = v;
    }
}

extern "C" void kernel_launch(void* const* d_in, const int* in_sizes, int n_in,
                              void* d_out, int out_size, void* d_ws, size_t ws_size,
                              hipStream_t stream) {
    const int*   counts = (const int*)d_in[0];
    const float* x      = (const float*)d_in[1];
    const float* W_ih   = (const float*)d_in[2];
    const float* W_hh   = (const float*)d_in[3];
    const float* b_ih   = (const float*)d_in[4];
    const float* b_hh   = (const float*)d_in[5];
    float* out = (float*)d_out;

    char* ws = (char*)d_ws;
    uint4* wt8 = (uint4*)ws;                                   // 512 KB
    float* u   = (float*)(ws + (512 << 10));                   // 128 KB
    float* hA  = (float*)(ws + (512 << 10) + (128 << 10));     // 128 KB
    float* hB  = (float*)(ws + (512 << 10) + (256 << 10));     // 128 KB
    int*   tstop = (int*)(ws + (512 << 10) + (384 << 10));     // 256 B

    hipLaunchKernelGGL(prep_kernel, dim3(128), dim3(512), 0, stream,
                       x, W_ih, W_hh, b_ih, b_hh, wt8, u);
    hipLaunchKernelGGL(rnn_kernel, dim3(B_), dim3(512), 0, stream,
                       counts, u, wt8, out, hA, hB, tstop);
    hipLaunchKernelGGL(fill_kernel, dim3(128, B_), dim3(256), 0, stream,
                       counts, tstop, hA, hB, out);
}

// Round 12
// 96.651 us; speedup vs baseline: 1.5325x; 1.0226x over previous
//
#include <hip/hip_runtime.h>
#include <hip/hip_bf16.h>
#include <math.h>

#define B_    64
#define L_    2048
#define D_    512
#define EPS   2.5e-3f

typedef _Float16 half2v __attribute__((ext_vector_type(2)));

// Packed f16 dot-2 with f32 accumulate (VOP3P v_dot2_f32_f16 via builtin).
__device__ inline float fdot2f(unsigned wu, unsigned hu, float acc) {
    return __builtin_amdgcn_fdot2(__builtin_bit_cast(half2v, wu),
                                  __builtin_bit_cast(half2v, hu), acc, false);
}

__device__ inline float fast_tanh(float x) {
    float e = __expf(2.0f * x);           // inf for large x is fine
    return 1.0f - 2.0f / (e + 1.0f);
}

// LDS-only barrier: waits this wave's LDS ops, then raw s_barrier.
// Does not drain vmcnt — output stores stay in flight across steps.
__device__ inline void lds_barrier() {
    asm volatile("s_waitcnt lgkmcnt(0)" ::: "memory");
    __builtin_amdgcn_s_barrier();
    __builtin_amdgcn_sched_barrier(0);
}

__device__ inline int clampc(int c) { return c < 0 ? 0 : (c > L_ ? L_ : c); }

__device__ inline unsigned packh(float lo, float hi) {
    half2v v; v[0] = (_Float16)lo; v[1] = (_Float16)hi;   // RNE casts
    return __builtin_bit_cast(unsigned, v);
}

union PackU { unsigned u; _Float16 h[2]; };

// blocks [0,64): u[b][d] = x[b]·W_ih[d] + b_ih[d] + b_hh[d]
// blocks [64,128): transpose+convert W_hh -> WT8 packed f16 pairs, PERMUTED:
//   entry [k8*512 + j*64 + lane] = W_hh[d=lane*8+j][8*k8 .. 8*k8+7]
__global__ __launch_bounds__(512) void prep_kernel(
    const float* __restrict__ x, const float* __restrict__ W_ih,
    const float* __restrict__ W_hh, const float* __restrict__ b_ih,
    const float* __restrict__ b_hh, uint4* __restrict__ wt8,
    float* __restrict__ u)
{
    const int blk = blockIdx.x;
    const int tid = threadIdx.x;
    if (blk < B_) {
        __shared__ float xs[D_];
        xs[tid] = x[blk * D_ + tid];
        __syncthreads();
        const float4* wrow = reinterpret_cast<const float4*>(W_ih + (size_t)tid * D_);
        const float4* xv   = reinterpret_cast<const float4*>(xs);
        float acc = b_ih[tid] + b_hh[tid];
        #pragma unroll 8
        for (int k = 0; k < D_ / 4; ++k) {
            float4 w = wrow[k]; float4 xx = xv[k];
            acc += w.x * xx.x + w.y * xx.y + w.z * xx.z + w.w * xx.w;
        }
        u[blk * D_ + tid] = acc;
    } else {
        const int k8   = blk - B_;
        const int j    = tid >> 6;          // 0..7
        const int lane = tid & 63;
        const int d    = lane * 8 + j;
        const float* wr = W_hh + (size_t)d * D_ + k8 * 8;
        unsigned o[4];
        #pragma unroll
        for (int i = 0; i < 4; ++i) {
            PackU p;
            p.h[0] = (_Float16)wr[2 * i];
            p.h[1] = (_Float16)wr[2 * i + 1];
            o[i] = p.u;
        }
        wt8[(size_t)k8 * D_ + j * 64 + lane] = make_uint4(o[0], o[1], o[2], o[3]);
    }
}

// 64 blocks x 512 threads, K-split across waves (R11 geometry), but:
//  - h stays in registers: wave w's slice h[64w..64w+64) lives in its own
//    lanes; pairs packed in-reg, broadcast via v_readlane -> SGPR -> dot2.
//  - ONE lds_barrier/step: partials double-buffered as f16 (pb16[2]).
//  - exit check one step delayed (flags visible after next barrier).
__global__ __launch_bounds__(512, 2) void rnn_kernel(
    const int* __restrict__ counts, const float* __restrict__ u,
    const uint4* __restrict__ wt8, float* __restrict__ out,
    float* __restrict__ hA, float* __restrict__ hB, int* __restrict__ tstop)
{
    const int b    = blockIdx.x;
    const int tid  = threadIdx.x;
    const int w    = tid >> 6;     // wave 0..7
    const int lane = tid & 63;
    const int w8   = w * 8;        // first owned K-chunk
    const int count = clampc(counts[b]);

    __shared__ __align__(16) uint4 wl[2][8][512];        // 128 KB (j=6,7 tails)
    __shared__ __align__(16) _Float16 pb16[2][8][D_];    // 16 KB partials, dbuf
    __shared__ int flag[2];

    // W loads j=0..5 into named regs (coalesced), j=6,7 into LDS.
    const uint4* wb = wt8 + (size_t)w8 * D_ + lane;
    #define WDEC(j) \
        uint4 w##j##_0 = wb[0*D_ + (j)*64]; uint4 w##j##_1 = wb[1*D_ + (j)*64]; \
        uint4 w##j##_2 = wb[2*D_ + (j)*64]; uint4 w##j##_3 = wb[3*D_ + (j)*64]; \
        uint4 w##j##_4 = wb[4*D_ + (j)*64]; uint4 w##j##_5 = wb[5*D_ + (j)*64]; \
        uint4 w##j##_6 = wb[6*D_ + (j)*64]; uint4 w##j##_7 = wb[7*D_ + (j)*64];
    WDEC(0) WDEC(1) WDEC(2) WDEC(3) WDEC(4) WDEC(5)
    #undef WDEC
    #pragma unroll
    for (int c = 0; c < 8; ++c) {
        wl[0][c][tid] = wb[c * D_ + 6 * 64];
        wl[1][c][tid] = wb[c * D_ + 7 * 64];
    }

    if (tid == 0) { flag[0] = -2; flag[1] = -2; }

    const float u_reg = u[b * D_ + tid];
    float* orow = out + (size_t)b * L_ * D_ + tid;
    __syncthreads();                       // full drain once (W loads -> LDS)

    float hval = 0.f, hprev = 0.f, hprev2 = 0.f;
    int   ts   = count;
    float aval = 0.f, bval = 0.f;

    for (int t = 0; t < count; ++t) {
        // ---- pack h pairs in-register (wave-local; h[64w+L] lives in lane L)
        const float pa = __shfl_xor(hval, 1, 64);
        const unsigned hp = (lane & 1) ? packh(pa, hval) : packh(hval, pa);

        float p0 = 0.f, p1 = 0.f, p2 = 0.f, p3 = 0.f;
        float p4 = 0.f, p5 = 0.f, p6 = 0.f, p7 = 0.f;

        #define STEPC(c) { \
            const unsigned hx = (unsigned)__builtin_amdgcn_readlane((int)hp, 8*(c)+0); \
            const unsigned hy = (unsigned)__builtin_amdgcn_readlane((int)hp, 8*(c)+2); \
            const unsigned hz = (unsigned)__builtin_amdgcn_readlane((int)hp, 8*(c)+4); \
            const unsigned hw = (unsigned)__builtin_amdgcn_readlane((int)hp, 8*(c)+6); \
            p0 = fdot2f(w0_##c.x, hx, p0); p0 = fdot2f(w0_##c.y, hy, p0); \
            p0 = fdot2f(w0_##c.z, hz, p0); p0 = fdot2f(w0_##c.w, hw, p0); \
            p1 = fdot2f(w1_##c.x, hx, p1); p1 = fdot2f(w1_##c.y, hy, p1); \
            p1 = fdot2f(w1_##c.z, hz, p1); p1 = fdot2f(w1_##c.w, hw, p1); \
            p2 = fdot2f(w2_##c.x, hx, p2); p2 = fdot2f(w2_##c.y, hy, p2); \
            p2 = fdot2f(w2_##c.z, hz, p2); p2 = fdot2f(w2_##c.w, hw, p2); \
            p3 = fdot2f(w3_##c.x, hx, p3); p3 = fdot2f(w3_##c.y, hy, p3); \
            p3 = fdot2f(w3_##c.z, hz, p3); p3 = fdot2f(w3_##c.w, hw, p3); \
            p4 = fdot2f(w4_##c.x, hx, p4); p4 = fdot2f(w4_##c.y, hy, p4); \
            p4 = fdot2f(w4_##c.z, hz, p4); p4 = fdot2f(w4_##c.w, hw, p4); \
            p5 = fdot2f(w5_##c.x, hx, p5); p5 = fdot2f(w5_##c.y, hy, p5); \
            p5 = fdot2f(w5_##c.z, hz, p5); p5 = fdot2f(w5_##c.w, hw, p5); \
            uint4 x6 = wl[0][c][tid]; \
            p6 = fdot2f(x6.x, hx, p6); p6 = fdot2f(x6.y, hy, p6); \
            p6 = fdot2f(x6.z, hz, p6); p6 = fdot2f(x6.w, hw, p6); \
            uint4 x7 = wl[1][c][tid]; \
            p7 = fdot2f(x7.x, hx, p7); p7 = fdot2f(x7.y, hy, p7); \
            p7 = fdot2f(x7.z, hz, p7); p7 = fdot2f(x7.w, hw, p7); }
        STEPC(0) STEPC(1) STEPC(2) STEPC(3)
        STEPC(4) STEPC(5) STEPC(6) STEPC(7)
        #undef STEPC

        // partials (f16, RNE) -> pb16[t&1][w][d=lane*8 .. +8) as one b128
        uint4 qv = make_uint4(packh(p0, p1), packh(p2, p3),
                              packh(p4, p5), packh(p6, p7));
        *reinterpret_cast<uint4*>(&pb16[t & 1][w][lane * 8]) = qv;

        lds_barrier();                     // the ONE barrier per step

        // ---- delayed exit check: flags from step t-1 are now visible
        if (t >= 3 && flag[(t - 1) & 1] != t - 1) {
            ts   = t;                      // h_{t-1}=h_{t-3} -> rows t.. periodic
            aval = hprev;                  // row t   (parity 0) = h_t ~ h_{t-2}
            bval = hval;                   // row t+1 (parity 1) = h_{t-1}
            break;
        }

        // ---- reduce output d = tid
        float s = u_reg;
        #pragma unroll
        for (int w2 = 0; w2 < 8; ++w2)
            s += (float)pb16[t & 1][w2][tid];

        const float h = fast_tanh(s);
        orow[(size_t)t * D_] = h;          // fire-and-forget

        const float df = fabsf(h - hprev); // |h_t - h_{t-2}|
        hprev2 = hprev; hprev = hval; hval = h;

        if (t < 2 || df > EPS) flag[t & 1] = t;   // benign same-value race
    }

    hA[b * D_ + tid] = aval;
    hB[b * D_ + tid] = bval;
    if (tid == 0) tstop[b] = ts;
}

// Rows [ts,count): alternate hA/hB by parity of (t-ts). Rows [count,L): zeros.
__global__ __launch_bounds__(256) void fill_kernel(
    const int* __restrict__ counts, const int* __restrict__ tstop,
    const float* __restrict__ hA, const float* __restrict__ hB,
    float* __restrict__ out)
{
    const int b   = blockIdx.y;
    const int c   = blockIdx.x;          // 128 chunks of 16 rows
    const int tid = threadIdx.x;
    const int count = clampc(counts[b]);
    const int ts  = tstop[b];

    const int d4   = tid & 127;
    const int rsub = tid >> 7;           // 0..1
    const float4 av = reinterpret_cast<const float4*>(hA + (size_t)b * D_)[d4];
    const float4 bv = reinterpret_cast<const float4*>(hB + (size_t)b * D_)[d4];
    const float4 z  = make_float4(0.f, 0.f, 0.f, 0.f);
    float4* ob = reinterpret_cast<float4*>(out + (size_t)b * L_ * D_);

    #pragma unroll
    for (int rr = 0; rr < 8; ++rr) {
        const int t = c * 16 + rr * 2 + rsub;
        if (t < ts) continue;
        float4 v = z;
        if (t < count) v = ((t - ts) & 1) ? bv : av;
        ob[(size_t)t * (D_ / 4) + d4] = v;
    }
}

extern "C" void kernel_launch(void* const* d_in, const int* in_sizes, int n_in,
                              void* d_out, int out_size, void* d_ws, size_t ws_size,
                              hipStream_t stream) {
    const int*   counts = (const int*)d_in[0];
    const float* x      = (const float*)d_in[1];
    const float* W_ih   = (const float*)d_in[2];
    const float* W_hh   = (const float*)d_in[3];
    const float* b_ih   = (const float*)d_in[4];
    const float* b_hh   = (const float*)d_in[5];
    float* out = (float*)d_out;

    char* ws = (char*)d_ws;
    uint4* wt8 = (uint4*)ws;                                   // 512 KB
    float* u   = (float*)(ws + (512 << 10));                   // 128 KB
    float* hA  = (float*)(ws + (512 << 10) + (128 << 10));     // 128 KB
    float* hB  = (float*)(ws + (512 << 10) + (256 << 10));     // 128 KB
    int*   tstop = (int*)(ws + (512 << 10) + (384 << 10));     // 256 B

    hipLaunchKernelGGL(prep_kernel, dim3(128), dim3(512), 0, stream,
                       x, W_ih, W_hh, b_ih, b_hh, wt8, u);
    hipLaunchKernelGGL(rnn_kernel, dim3(B_), dim3(512), 0, stream,
                       counts, u, wt8, out, hA, hB, tstop);
    hipLaunchKernelGGL(fill_kernel, dim3(128, B_), dim3(256), 0, stream,
                       counts, tstop, hA, hB, out);
}